// Round 6
// baseline (232.249 us; speedup 1.0000x reference)
//
#include <hip/hip_runtime.h>

#define DMODEL 1024
#define NHEAD  16
#define HWID   64
#define FFDIM  4096
#define NBATCH 2
#define SEQT   2048
#define NTOK   4096   // NBATCH*SEQT
#define QKLD   3072   // qkv row stride

using bf8    = __attribute__((ext_vector_type(8))) short;
using f32x4  = __attribute__((ext_vector_type(4))) float;
using f32x16 = __attribute__((ext_vector_type(16))) float;

__device__ inline short to_bf16(float f) {
  unsigned u = __float_as_uint(f);
  return (short)((u + 0x7fffu + ((u >> 16) & 1u)) >> 16);
}
__device__ inline float from_bf16(short s) {
  return __uint_as_float(((unsigned)(unsigned short)s) << 16);
}
__device__ inline float exp2_fast(float x) {
  float r;
  asm("v_exp_f32 %0, %1" : "=v"(r) : "v"(x));
  return r;
}
__device__ inline unsigned cvt_pk_bf16(float lo, float hi) {
  unsigned r;
  asm("v_cvt_pk_bf16_f32 %0, %1, %2" : "=v"(r) : "v"(lo), "v"(hi));
  return r;
}
__device__ inline void lds_load16(const void* g, void* l) {
  __builtin_amdgcn_global_load_lds(
      (const __attribute__((address_space(1))) void*)g,
      (__attribute__((address_space(3))) void*)l, 16, 0, 0);
}

// ---------------- all weights f32 -> bf16 in one launch ----------------
__global__ __launch_bounds__(256)
void cvt_all(const float* __restrict__ Wq, const float* __restrict__ Wk,
             const float* __restrict__ Wv, const float* __restrict__ W1,
             const float* __restrict__ W2, short* __restrict__ wqkv,
             short* __restrict__ w1b, short* __restrict__ w2b) {
  int i = blockIdx.x * 256 + threadIdx.x;   // float4 index, total 2883584
  const float* src;
  short* dst;
  if (i < 1048576)      { src = W1; dst = w1b; }
  else if (i < 2097152) { src = W2; dst = w2b;            i -= 1048576; }
  else if (i < 2359296) { src = Wq; dst = wqkv;           i -= 2097152; }
  else if (i < 2621440) { src = Wk; dst = wqkv + 1048576; i -= 2359296; }
  else                  { src = Wv; dst = wqkv + 2097152; i -= 2621440; }
  float4 v = ((const float4*)src)[i];
  short4 o;
  o.x = to_bf16(v.x); o.y = to_bf16(v.y);
  o.z = to_bf16(v.z); o.w = to_bf16(v.w);
  ((short4*)dst)[i] = o;
}

// ---------------- LayerNorm (f32 in -> bf16 out) ----------------
__global__ __launch_bounds__(256)
void ln_kernel(const float* __restrict__ x, const float* __restrict__ g,
               const float* __restrict__ b, short* __restrict__ out) {
  const int row = blockIdx.x;
  const int t = threadIdx.x;
  const float4 v = ((const float4*)(x + (long)row * DMODEL))[t];
  float s  = v.x + v.y + v.z + v.w;
  float s2 = v.x * v.x + v.y * v.y + v.z * v.z + v.w * v.w;
#pragma unroll
  for (int m = 1; m < 64; m <<= 1) {
    s  += __shfl_xor(s, m);
    s2 += __shfl_xor(s2, m);
  }
  __shared__ float red[8];
  if ((t & 63) == 0) { red[t >> 6] = s; red[4 + (t >> 6)] = s2; }
  __syncthreads();
  s  = red[0] + red[1] + red[2] + red[3];
  s2 = red[4] + red[5] + red[6] + red[7];
  const float mu = s * (1.f / DMODEL);
  const float rs = rsqrtf(s2 * (1.f / DMODEL) - mu * mu + 1e-5f);
  const float4 gv = ((const float4*)g)[t];
  const float4 bv = ((const float4*)b)[t];
  short4 o;
  o.x = to_bf16((v.x - mu) * rs * gv.x + bv.x);
  o.y = to_bf16((v.y - mu) * rs * gv.y + bv.y);
  o.z = to_bf16((v.z - mu) * rs * gv.z + bv.z);
  o.w = to_bf16((v.w - mu) * rs * gv.w + bv.w);
  ((short4*)(out + (long)row * DMODEL))[t] = o;
}

// ---- 4-wave 128x128 NT GEMM, 3-slot ring, depth-2 prefetch, 1 barrier/tile
// C[M][N] = A[M][K_all sliced]*Bw[N][..]^T.
// EPI 0: bf16 store; 1: SiLU bf16; 3: f32 atomicAdd into Cout (residual there).
template <int EPI>
__global__ __launch_bounds__(256, 3)
void gemm4(const short* __restrict__ A, const short* __restrict__ Bw,
           void* __restrict__ Cout, int N, int lda, int ldb, int Kslice) {
  __shared__ short lds[3][2][4096];   // [slot][A|B][128 rows x 32 cols] = 48 KiB
  const int tid = threadIdx.x;
  const int w = tid >> 6, lane = tid & 63;
  const int l15 = lane & 15, l4 = lane >> 4;
  const int wr = (w >> 1) * 64, wc = (w & 1) * 64;

  // XCD chunk + 4x4 supertile (needs gx%4==0, gy%4==0, nwg%8==0)
  const int gx = gridDim.x, nwg = gx * gridDim.y;
  const int wg = blockIdx.y * gx + blockIdx.x;
  const int sw = (wg & 7) * (nwg >> 3) + (wg >> 3);
  const int sx = gx >> 2;
  const int st = sw >> 4, w16 = sw & 15;
  const long bm = (long)((st / sx) * 4 + (w16 >> 2)) * 128;
  const long bn = (long)((st % sx) * 4 + (w16 & 3)) * 128;
  const long kofs = (long)blockIdx.z * Kslice;

  // staging source offsets (source pre-swizzled, LDS dest linear)
  long aoff[2], boff[2];
#pragma unroll
  for (int i = 0; i < 2; ++i) {
    const int c = i * 4 + w;                 // 1KB chunk 0..7
    const int row = c * 16 + (lane >> 2);
    const int slog = (lane & 3) ^ ((row >> 1) & 3);
    aoff[i] = (bm + row) * (long)lda + slog * 8 + kofs;
    boff[i] = (bn + row) * (long)ldb + slog * 8 + kofs;
  }
  // swizzled LDS read byte-offsets
  int offA[4], offB[4];
#pragma unroll
  for (int m = 0; m < 4; ++m) {
    const int row = wr + m * 16 + l15;
    offA[m] = row * 64 + ((l4 ^ ((row >> 1) & 3)) << 4);
  }
#pragma unroll
  for (int n = 0; n < 4; ++n) {
    const int row = wc + n * 16 + l15;
    offB[n] = row * 64 + ((l4 ^ ((row >> 1) & 3)) << 4);
  }

  const int NT = Kslice >> 5;
  f32x4 acc[4][4] = {};

  // prologue: stage tiles 0,1
#pragma unroll
  for (int t = 0; t < 2; ++t) {
    char* db = (char*)&lds[t][0][0];
#pragma unroll
    for (int i = 0; i < 2; ++i) {
      const int c = i * 4 + w;
      lds_load16(A  + aoff[i] + t * 32, db + c * 1024);
      lds_load16(Bw + boff[i] + t * 32, db + 8192 + c * 1024);
    }
  }

  int slot = 0, pslot = 2;
  for (int t = 0; t < NT; ++t) {
    if (t + 1 < NT) asm volatile("s_waitcnt vmcnt(4)" ::: "memory");
    else            asm volatile("s_waitcnt vmcnt(0)" ::: "memory");
    __builtin_amdgcn_s_barrier();
    asm volatile("" ::: "memory");
    if (t + 2 < NT) {               // stage tile t+2 into ring slot
      char* db = (char*)&lds[pslot][0][0];
      const long ks = (long)(t + 2) * 32;
#pragma unroll
      for (int i = 0; i < 2; ++i) {
        const int c = i * 4 + w;
        lds_load16(A  + aoff[i] + ks, db + c * 1024);
        lds_load16(Bw + boff[i] + ks, db + 8192 + c * 1024);
      }
    }
    const char* sb = (const char*)&lds[slot][0][0];
    bf8 af[4], bfr[4];
#pragma unroll
    for (int m = 0; m < 4; ++m) af[m] = *(const bf8*)(sb + offA[m]);
#pragma unroll
    for (int n = 0; n < 4; ++n) bfr[n] = *(const bf8*)(sb + 8192 + offB[n]);
    __builtin_amdgcn_s_setprio(1);
#pragma unroll
    for (int m = 0; m < 4; ++m)
#pragma unroll
      for (int n = 0; n < 4; ++n)
        acc[m][n] = __builtin_amdgcn_mfma_f32_16x16x32_bf16(af[m], bfr[n], acc[m][n], 0, 0, 0);
    __builtin_amdgcn_s_setprio(0);
    slot  = (slot  == 2) ? 0 : slot  + 1;
    pslot = (pslot == 2) ? 0 : pslot + 1;
  }

  // ---------- epilogue ----------
#pragma unroll
  for (int m = 0; m < 4; ++m)
#pragma unroll
    for (int n = 0; n < 4; ++n) {
      const long col = bn + wc + n * 16 + l15;
#pragma unroll
      for (int r = 0; r < 4; ++r) {
        const long row = bm + wr + m * 16 + l4 * 4 + r;
        float v = acc[m][n][r];
        if (EPI == 0) {
          ((short*)Cout)[row * N + col] = to_bf16(v);
        } else if (EPI == 1) {
          ((short*)Cout)[row * N + col] = to_bf16(v / (1.f + __expf(-v)));
        } else {
          atomicAdd(&((float*)Cout)[row * N + col], v);  // resid pre-loaded
        }
      }
    }
}

// ---------------- K pack + V pack, one launch ----------------
// x<64: Kp[bh][g(32tok)][c][lane64]; x>=64: Vp[bh][dg][chg][lane64] (V^T)
__global__ __launch_bounds__(256)
void pack_kv(const short* __restrict__ qkv, short* __restrict__ Kp,
             short* __restrict__ Vp) {
  __shared__ short tile[64][72];
  const int bx = blockIdx.x, bh = blockIdx.y;
  const int b = bh >> 4, h = bh & 15;
  const int t = threadIdx.x;
  if (bx < 64) {
    const int g = bx;
    const int row = t >> 3, cc = t & 7, c = cc >> 1, hi = cc & 1;
    const bf8 v = *(const bf8*)&qkv[(long)(b * SEQT + g * 32 + row) * QKLD +
                                    1024 + h * HWID + c * 16 + hi * 8];
    *(bf8*)&Kp[(((long)bh * 256 + g * 4 + c) * 64 + hi * 32 + row) * 8] = v;
  } else {
    const int tc = bx - 64;
    {
      const int r = t >> 2, c = (t & 3) * 16;
      const long src = (long)(b * SEQT + tc * 64 + r) * QKLD + 2048 + h * HWID + c;
      *(bf8*)&tile[r][c]     = *(const bf8*)&qkv[src];
      *(bf8*)&tile[r][c + 8] = *(const bf8*)&qkv[src + 8];
    }
    __syncthreads();
    const int dg = t >> 7, ch = (t >> 5) & 3, row = t & 31;
#pragma unroll
    for (int hi = 0; hi < 2; ++hi) {
      short o[8];
#pragma unroll
      for (int j = 0; j < 8; ++j) o[j] = tile[ch * 16 + hi * 8 + j][dg * 32 + row];
      *(bf8*)&Vp[(((long)bh * 256 + dg * 128 + tc * 4 + ch) * 64 + hi * 32 + row) * 8] =
          *(bf8*)o;
    }
  }
}

// ---------------- Flash attention: 1 warp = 32 q rows, packed K/V frags ----
__global__ __launch_bounds__(64, 2)
void attn_kernel(const short* __restrict__ qkv, const short* __restrict__ Kp,
                 const short* __restrict__ Vp, const short* __restrict__ xn,
                 float* __restrict__ att) {
  const int L = blockIdx.x;
  const int bh = (L & 7) * 4 + ((L >> 3) & 3);
  const int qtile = 63 - (L >> 5);
  const int b = bh >> 4, h = bh & 15;
  const int q0 = qtile * 32;
  const int lane = threadIdx.x;
  const int l31 = lane & 31, hi = lane >> 5;
  const long tokbase = (long)b * SEQT;

  bf8 qf[4];
  {
    const short* qrow = qkv + (tokbase + q0 + l31) * QKLD + h * HWID + hi * 8;
#pragma unroll
    for (int c = 0; c < 4; ++c) qf[c] = *(const bf8*)(qrow + c * 16);
  }

  const float slope2 = exp2f(-0.5f * (float)(h + 1)) * 1.44269504f;
  const float sc2 = 0.125f * 1.44269504f;
  float arr[16];
#pragma unroll
  for (int r = 0; r < 16; ++r) arr[r] = slope2 * (float)((r & 3) + 8 * (r >> 2));
  const float hofs = slope2 * 4.f * (float)hi;
  const float qabs = (float)(q0 + l31);

  float m2 = -1e30f, lsum = 0.f;
  f32x16 acc0 = {}, acc1 = {};
  const int ktm = q0 >> 6;
  const bf8* kfb = (const bf8*)Kp + (long)bh * 16384 + lane;
  const bf8* vfb = (const bf8*)Vp + (long)bh * 16384 + lane;

  bf8 kc[8], kn[8], vc[8];
#pragma unroll
  for (int c = 0; c < 4; ++c) {
    kc[c]     = kfb[c * 64];
    kc[4 + c] = kfb[256 + c * 64];
  }

#pragma unroll 2
  for (int kt = 0; kt <= ktm; ++kt) {
    const int k0 = kt * 64;
    const long vb = (long)kt * 256;
#pragma unroll
    for (int ch = 0; ch < 4; ++ch) {
      vc[ch]     = vfb[vb + ch * 64];
      vc[4 + ch] = vfb[8192 + vb + ch * 64];
    }
    const long nb = (long)(kt < ktm ? kt + 1 : kt) * 512;
#pragma unroll
    for (int c = 0; c < 4; ++c) {
      kn[c]     = kfb[nb + c * 64];
      kn[4 + c] = kfb[nb + 256 + c * 64];
    }
    f32x16 s0 = {}, s1 = {};
#pragma unroll
    for (int c = 0; c < 4; ++c) {
      s0 = __builtin_amdgcn_mfma_f32_32x32x16_bf16(kc[c], qf[c], s0, 0, 0, 0);
      s1 = __builtin_amdgcn_mfma_f32_32x32x16_bf16(kc[4 + c], qf[c], s1, 0, 0, 0);
    }
    const float base = slope2 * ((float)k0 - qabs) + hofs;
    float s[32];
#pragma unroll
    for (int r = 0; r < 16; ++r) {
      s[r]      = fmaf(s0[r], sc2, base + arr[r]);
      s[16 + r] = fmaf(s1[r], sc2, base + arr[r] + slope2 * 32.f);
    }
    if (kt == ktm) {
      const int qi = q0 + l31;
#pragma unroll
      for (int r = 0; r < 16; ++r) {
        const int krel = (r & 3) + 8 * (r >> 2) + 4 * hi;
        if (k0 + krel > qi)      s[r]      = -1e30f;
        if (k0 + 32 + krel > qi) s[16 + r] = -1e30f;
      }
    }
    float ma = s[0], mb = s[1], mc = s[2], md = s[3];
#pragma unroll
    for (int i = 4; i < 32; i += 4) {
      ma = fmaxf(ma, s[i]); mb = fmaxf(mb, s[i + 1]);
      mc = fmaxf(mc, s[i + 2]); md = fmaxf(md, s[i + 3]);
    }
    float pm = fmaxf(fmaxf(ma, mb), fmaxf(mc, md));
    pm = fmaxf(pm, __shfl_xor(pm, 32));
    if (!__all(pm - m2 <= 11.0f)) {
      const float nm = fmaxf(m2, pm);
      const float alpha = exp2_fast(m2 - nm);
      m2 = nm;
      lsum *= alpha;
      acc0 *= alpha;
      acc1 *= alpha;
    }
    float p[32];
#pragma unroll
    for (int i = 0; i < 32; ++i) p[i] = exp2_fast(s[i] - m2);
    float sa = p[0], sb = p[1], sc = p[2], sd = p[3];
#pragma unroll
    for (int i = 4; i < 32; i += 4) {
      sa += p[i]; sb += p[i + 1]; sc += p[i + 2]; sd += p[i + 3];
    }
    float rs = (sa + sb) + (sc + sd);
    rs += __shfl_xor(rs, 32);
    lsum += rs;
    unsigned cpk[16];
#pragma unroll
    for (int g = 0; g < 8; ++g) {
      cpk[g]     = cvt_pk_bf16(p[2 * g], p[2 * g + 1]);
      cpk[8 + g] = cvt_pk_bf16(p[16 + 2 * g], p[16 + 2 * g + 1]);
    }
    bf8 pb[4];
#pragma unroll
    for (int ch = 0; ch < 4; ++ch) {
      const int cb = (ch >> 1) * 8 + (ch & 1) * 4;
      unsigned u0 = cpk[cb + 0], u2 = cpk[cb + 2];
      unsigned u1 = cpk[cb + 1], u3 = cpk[cb + 3];
      asm("v_permlane32_swap_b32 %0, %1" : "+v"(u0), "+v"(u2));
      asm("v_permlane32_swap_b32 %0, %1" : "+v"(u1), "+v"(u3));
      union { unsigned u[4]; bf8 v; } f;
      f.u[0] = u0; f.u[1] = u1; f.u[2] = u2; f.u[3] = u3;
      pb[ch] = f.v;
    }
#pragma unroll
    for (int ch = 0; ch < 4; ++ch) {
      acc0 = __builtin_amdgcn_mfma_f32_32x32x16_bf16(vc[ch], pb[ch], acc0, 0, 0, 0);
      acc1 = __builtin_amdgcn_mfma_f32_32x32x16_bf16(vc[4 + ch], pb[ch], acc1, 0, 0, 0);
    }
#pragma unroll
    for (int i = 0; i < 8; ++i) kc[i] = kn[i];
  }

  __shared__ float Os[32 * 68];
  const float rl = 1.f / lsum;
#pragma unroll
  for (int r = 0; r < 16; ++r) {
    const int d0 = (r & 3) + 8 * (r >> 2) + 4 * hi;
    Os[l31 * 68 + d0]      = acc0[r] * rl;
    Os[l31 * 68 + 32 + d0] = acc1[r] * rl;
  }
  __syncthreads();
#pragma unroll
  for (int it = 0; it < 8; ++it) {
    const int idx = it * 64 + lane;
    const int row = idx >> 4, c4 = idx & 15;
    const float4 ov = *(const float4*)&Os[row * 68 + c4 * 4];
    const long gbase = (tokbase + q0 + row) * DMODEL + h * HWID + c4 * 4;
    const short4 xv = *(const short4*)&xn[gbase];
    float4 o;
    o.x = ov.x + from_bf16(xv.x);
    o.y = ov.y + from_bf16(xv.y);
    o.z = ov.z + from_bf16(xv.z);
    o.w = ov.w + from_bf16(xv.w);
    *(float4*)&att[gbase] = o;
  }
}

// ---------------- launcher ----------------
extern "C" void kernel_launch(void* const* d_in, const int* in_sizes, int n_in,
                              void* d_out, int out_size, void* d_ws, size_t ws_size,
                              hipStream_t stream) {
  (void)in_sizes; (void)n_in; (void)out_size; (void)ws_size;
  const float* x  = (const float*)d_in[0];
  const float* Wq = (const float*)d_in[1];
  const float* Wk = (const float*)d_in[2];
  const float* Wv = (const float*)d_in[3];
  const float* W1 = (const float*)d_in[4];
  const float* W2 = (const float*)d_in[5];
  const float* g1 = (const float*)d_in[6];
  const float* b1 = (const float*)d_in[7];
  const float* g2 = (const float*)d_in[8];
  const float* b2 = (const float*)d_in[9];

  char* ws = (char*)d_ws;
  const size_t MB = 1024 * 1024;
  short* wqkv_b = (short*)(ws + 0);        // 6 MB [3072][1024]
  short* w1_b   = (short*)(ws + 6  * MB);  // 8 MB
  short* w2_b   = (short*)(ws + 14 * MB);  // 8 MB
  short* xn     = (short*)(ws + 22 * MB);  // 8 MB [NTOK][D]
  short* qkv    = (short*)(ws + 30 * MB);  // 24 MB [NTOK][3072]
  short* m1     = (short*)(ws + 22 * MB);  // 32 MB (aliases xn+qkv, dead after attn)
  short* Kp     = (short*)(ws + 54 * MB);  // 8 MB packed K fragments
  short* Vp     = (short*)(ws + 62 * MB);  // 8 MB packed V fragments
  short* hb     = (short*)(ws + 70 * MB);  // 8 MB [NTOK][D]
  float* att    = (float*)d_out;           // att lives in d_out (mlp2 residual)

  cvt_all<<<11264, 256, 0, stream>>>(Wq, Wk, Wv, W1, W2, wqkv_b, w1_b, w2_b);

  ln_kernel<<<NTOK, 256, 0, stream>>>(x, g1, b1, xn);

  // fused QKV: [NTOK][3072]
  gemm4<0><<<dim3(24, 32), 256, 0, stream>>>(xn, wqkv_b, qkv, QKLD, DMODEL, DMODEL, DMODEL);
  pack_kv<<<dim3(96, 32), 256, 0, stream>>>(qkv, Kp, Vp);

  attn_kernel<<<2048, 64, 0, stream>>>(qkv, Kp, Vp, xn, att);

  ln_kernel<<<NTOK, 256, 0, stream>>>(att, g2, b2, hb);

  // MLP1: m1 = silu(hb * w1^T)
  gemm4<1><<<dim3(32, 32), 256, 0, stream>>>(hb, w1_b, m1, FFDIM, DMODEL, DMODEL, DMODEL);
  // MLP2 split-K=4, atomic combine into d_out (att residual already there)
  gemm4<3><<<dim3(8, 32, 4), 256, 0, stream>>>(m1, w2_b, d_out, DMODEL, FFDIM, FFDIM, 1024);
}

// Round 7
// 205.019 us; speedup vs baseline: 1.1328x; 1.1328x over previous
//
#include <hip/hip_runtime.h>

#define DMODEL 1024
#define NHEAD  16
#define HWID   64
#define FFDIM  4096
#define NBATCH 2
#define SEQT   2048
#define NTOK   4096   // NBATCH*SEQT
#define QKLD   3072   // qkv row stride

using bf8    = __attribute__((ext_vector_type(8))) short;
using f32x4  = __attribute__((ext_vector_type(4))) float;
using f32x16 = __attribute__((ext_vector_type(16))) float;

__device__ inline short to_bf16(float f) {
  unsigned u = __float_as_uint(f);
  return (short)((u + 0x7fffu + ((u >> 16) & 1u)) >> 16);
}
__device__ inline float from_bf16(short s) {
  return __uint_as_float(((unsigned)(unsigned short)s) << 16);
}
__device__ inline float exp2_fast(float x) {
  float r;
  asm("v_exp_f32 %0, %1" : "=v"(r) : "v"(x));
  return r;
}
__device__ inline unsigned cvt_pk_bf16(float lo, float hi) {
  unsigned r;
  asm("v_cvt_pk_bf16_f32 %0, %1, %2" : "=v"(r) : "v"(lo), "v"(hi));
  return r;
}
__device__ inline void lds_load16(const void* g, void* l) {
  __builtin_amdgcn_global_load_lds(
      (const __attribute__((address_space(1))) void*)g,
      (__attribute__((address_space(3))) void*)l, 16, 0, 0);
}

// ---------------- all weights f32 -> bf16 in one launch ----------------
__global__ __launch_bounds__(256)
void cvt_all(const float* __restrict__ Wq, const float* __restrict__ Wk,
             const float* __restrict__ Wv, const float* __restrict__ W1,
             const float* __restrict__ W2, short* __restrict__ wqkv,
             short* __restrict__ w1b, short* __restrict__ w2b) {
  int i = blockIdx.x * 256 + threadIdx.x;   // float4 index, total 2883584
  const float* src;
  short* dst;
  if (i < 1048576)      { src = W1; dst = w1b; }
  else if (i < 2097152) { src = W2; dst = w2b;            i -= 1048576; }
  else if (i < 2359296) { src = Wq; dst = wqkv;           i -= 2097152; }
  else if (i < 2621440) { src = Wk; dst = wqkv + 1048576; i -= 2359296; }
  else                  { src = Wv; dst = wqkv + 2097152; i -= 2621440; }
  float4 v = ((const float4*)src)[i];
  short4 o;
  o.x = to_bf16(v.x); o.y = to_bf16(v.y);
  o.z = to_bf16(v.z); o.w = to_bf16(v.w);
  ((short4*)dst)[i] = o;
}

// ---------------- LayerNorm (f32 in -> bf16 out) ----------------
__global__ __launch_bounds__(256)
void ln_kernel(const float* __restrict__ x, const float* __restrict__ g,
               const float* __restrict__ b, short* __restrict__ out) {
  const int row = blockIdx.x;
  const int t = threadIdx.x;
  const float4 v = ((const float4*)(x + (long)row * DMODEL))[t];
  float s  = v.x + v.y + v.z + v.w;
  float s2 = v.x * v.x + v.y * v.y + v.z * v.z + v.w * v.w;
#pragma unroll
  for (int m = 1; m < 64; m <<= 1) {
    s  += __shfl_xor(s, m);
    s2 += __shfl_xor(s2, m);
  }
  __shared__ float red[8];
  if ((t & 63) == 0) { red[t >> 6] = s; red[4 + (t >> 6)] = s2; }
  __syncthreads();
  s  = red[0] + red[1] + red[2] + red[3];
  s2 = red[4] + red[5] + red[6] + red[7];
  const float mu = s * (1.f / DMODEL);
  const float rs = rsqrtf(s2 * (1.f / DMODEL) - mu * mu + 1e-5f);
  const float4 gv = ((const float4*)g)[t];
  const float4 bv = ((const float4*)b)[t];
  short4 o;
  o.x = to_bf16((v.x - mu) * rs * gv.x + bv.x);
  o.y = to_bf16((v.y - mu) * rs * gv.y + bv.y);
  o.z = to_bf16((v.z - mu) * rs * gv.z + bv.z);
  o.w = to_bf16((v.w - mu) * rs * gv.w + bv.w);
  ((short4*)(out + (long)row * DMODEL))[t] = o;
}

// ---- 4-wave 256x128 NT GEMM (wave tile 128x64), 3-slot ring, depth-2,
//      1 barrier/tile, counted vmcnt(6).
// C[M][N] = A[M][Ksliced]*Bw[N][..]^T.
// EPI 0: bf16 store; 1: SiLU bf16; 2: f32 store into parts + z*zstride.
template <int EPI>
__global__ __launch_bounds__(256, 2)
void gemm4(const short* __restrict__ A, const short* __restrict__ Bw,
           void* __restrict__ Cout, int N, int lda, int ldb, int Kslice,
           long zstride) {
  __shared__ short lds[3][12288];   // slot = [A 256x32 | B 128x32] = 24 KiB
  const int tid = threadIdx.x;
  const int w = tid >> 6, lane = tid & 63;
  const int l15 = lane & 15, l4 = lane >> 4;
  const int wm = w >> 1, wn = w & 1;   // wave tile: rows wm*128, cols wn*64

  // XCD chunk + 4x4 supertile (gx%4==0, gy%4==0, nwg%8==0)
  const int gx = gridDim.x, nwg = gx * gridDim.y;
  const int wg = blockIdx.y * gx + blockIdx.x;
  const int sw = (wg & 7) * (nwg >> 3) + (wg >> 3);
  const int sx = gx >> 2;
  const int st = sw >> 4, w16 = sw & 15;
  const long bm = (long)((st / sx) * 4 + (w16 >> 2)) * 256;
  const long bn = (long)((st % sx) * 4 + (w16 & 3)) * 128;
  const long kofs = (long)blockIdx.z * Kslice;

  // staging source offsets (source pre-swizzled, LDS dest linear)
  long aoff[4], boff[2];
#pragma unroll
  for (int i = 0; i < 4; ++i) {
    const int c = i * 4 + w;                 // A chunk 0..15
    const int row = c * 16 + (lane >> 2);
    const int slog = (lane & 3) ^ ((row >> 1) & 3);
    aoff[i] = (bm + row) * (long)lda + slog * 8 + kofs;
  }
#pragma unroll
  for (int i = 0; i < 2; ++i) {
    const int c = i * 4 + w;                 // B chunk 0..7
    const int row = c * 16 + (lane >> 2);
    const int slog = (lane & 3) ^ ((row >> 1) & 3);
    boff[i] = (bn + row) * (long)ldb + slog * 8 + kofs;
  }
  // swizzled LDS read byte-offsets
  int offA[8], offB[4];
#pragma unroll
  for (int m = 0; m < 8; ++m) {
    const int row = wm * 128 + m * 16 + l15;
    offA[m] = row * 64 + ((l4 ^ ((row >> 1) & 3)) << 4);
  }
#pragma unroll
  for (int n = 0; n < 4; ++n) {
    const int row = wn * 64 + n * 16 + l15;
    offB[n] = row * 64 + ((l4 ^ ((row >> 1) & 3)) << 4);
  }

  const int NT = Kslice >> 5;
  f32x4 acc[8][4] = {};

  // prologue: stage tiles 0,1 (6 loads/wave each)
#pragma unroll
  for (int t = 0; t < 2; ++t) {
    char* db = (char*)&lds[t][0];
#pragma unroll
    for (int i = 0; i < 4; ++i)
      lds_load16(A + aoff[i] + t * 32, db + (i * 4 + w) * 1024);
#pragma unroll
    for (int i = 0; i < 2; ++i)
      lds_load16(Bw + boff[i] + t * 32, db + 16384 + (i * 4 + w) * 1024);
  }

  int slot = 0, pslot = 2;
  for (int t = 0; t < NT; ++t) {
    // in-order vmcnt: drains tile t's 6 loads; tile t+1's may stay in flight
    if (t + 1 < NT) asm volatile("s_waitcnt vmcnt(6)" ::: "memory");
    else            asm volatile("s_waitcnt vmcnt(0)" ::: "memory");
    __builtin_amdgcn_s_barrier();
    asm volatile("" ::: "memory");
    if (t + 2 < NT) {               // stage tile t+2 into ring slot
      char* db = (char*)&lds[pslot][0];
      const long ks = (long)(t + 2) * 32;
#pragma unroll
      for (int i = 0; i < 4; ++i)
        lds_load16(A + aoff[i] + ks, db + (i * 4 + w) * 1024);
#pragma unroll
      for (int i = 0; i < 2; ++i)
        lds_load16(Bw + boff[i] + ks, db + 16384 + (i * 4 + w) * 1024);
    }
    const char* sb = (const char*)&lds[slot][0];
    bf8 af[8], bfr[4];
#pragma unroll
    for (int m = 0; m < 8; ++m) af[m] = *(const bf8*)(sb + offA[m]);
#pragma unroll
    for (int n = 0; n < 4; ++n) bfr[n] = *(const bf8*)(sb + 16384 + offB[n]);
    __builtin_amdgcn_s_setprio(1);
#pragma unroll
    for (int m = 0; m < 8; ++m)
#pragma unroll
      for (int n = 0; n < 4; ++n)
        acc[m][n] = __builtin_amdgcn_mfma_f32_16x16x32_bf16(af[m], bfr[n], acc[m][n], 0, 0, 0);
    __builtin_amdgcn_s_setprio(0);
    slot  = (slot  == 2) ? 0 : slot  + 1;
    pslot = (pslot == 2) ? 0 : pslot + 1;
  }

  // ---------- epilogue ----------
  float* Cp = (float*)Cout + (EPI == 2 ? (long)blockIdx.z * zstride : 0);
#pragma unroll
  for (int m = 0; m < 8; ++m)
#pragma unroll
    for (int n = 0; n < 4; ++n) {
      const long col = bn + wn * 64 + n * 16 + l15;
#pragma unroll
      for (int r = 0; r < 4; ++r) {
        const long row = bm + wm * 128 + m * 16 + l4 * 4 + r;
        float v = acc[m][n][r];
        if (EPI == 0) {
          ((short*)Cout)[row * N + col] = to_bf16(v);
        } else if (EPI == 1) {
          ((short*)Cout)[row * N + col] = to_bf16(v / (1.f + __expf(-v)));
        } else {
          Cp[row * N + col] = v;
        }
      }
    }
}

// ---------------- K pack + V pack, one launch ----------------
__global__ __launch_bounds__(256)
void pack_kv(const short* __restrict__ qkv, short* __restrict__ Kp,
             short* __restrict__ Vp) {
  __shared__ short tile[64][72];
  const int bx = blockIdx.x, bh = blockIdx.y;
  const int b = bh >> 4, h = bh & 15;
  const int t = threadIdx.x;
  if (bx < 64) {
    const int g = bx;
    const int row = t >> 3, cc = t & 7, c = cc >> 1, hi = cc & 1;
    const bf8 v = *(const bf8*)&qkv[(long)(b * SEQT + g * 32 + row) * QKLD +
                                    1024 + h * HWID + c * 16 + hi * 8];
    *(bf8*)&Kp[(((long)bh * 256 + g * 4 + c) * 64 + hi * 32 + row) * 8] = v;
  } else {
    const int tc = bx - 64;
    {
      const int r = t >> 2, c = (t & 3) * 16;
      const long src = (long)(b * SEQT + tc * 64 + r) * QKLD + 2048 + h * HWID + c;
      *(bf8*)&tile[r][c]     = *(const bf8*)&qkv[src];
      *(bf8*)&tile[r][c + 8] = *(const bf8*)&qkv[src + 8];
    }
    __syncthreads();
    const int dg = t >> 7, ch = (t >> 5) & 3, row = t & 31;
#pragma unroll
    for (int hi = 0; hi < 2; ++hi) {
      short o[8];
#pragma unroll
      for (int j = 0; j < 8; ++j) o[j] = tile[ch * 16 + hi * 8 + j][dg * 32 + row];
      *(bf8*)&Vp[(((long)bh * 256 + dg * 128 + tc * 4 + ch) * 64 + hi * 32 + row) * 8] =
          *(bf8*)o;
    }
  }
}

// ---------------- Flash attention: 1 warp = 32 q rows, packed K/V frags ----
__global__ __launch_bounds__(64, 2)
void attn_kernel(const short* __restrict__ qkv, const short* __restrict__ Kp,
                 const short* __restrict__ Vp, const short* __restrict__ xn,
                 float* __restrict__ att) {
  const int L = blockIdx.x;
  const int bh = (L & 7) * 4 + ((L >> 3) & 3);
  const int qtile = 63 - (L >> 5);
  const int b = bh >> 4, h = bh & 15;
  const int q0 = qtile * 32;
  const int lane = threadIdx.x;
  const int l31 = lane & 31, hi = lane >> 5;
  const long tokbase = (long)b * SEQT;

  bf8 qf[4];
  {
    const short* qrow = qkv + (tokbase + q0 + l31) * QKLD + h * HWID + hi * 8;
#pragma unroll
    for (int c = 0; c < 4; ++c) qf[c] = *(const bf8*)(qrow + c * 16);
  }

  const float slope2 = exp2f(-0.5f * (float)(h + 1)) * 1.44269504f;
  const float sc2 = 0.125f * 1.44269504f;
  float arr[16];
#pragma unroll
  for (int r = 0; r < 16; ++r) arr[r] = slope2 * (float)((r & 3) + 8 * (r >> 2));
  const float hofs = slope2 * 4.f * (float)hi;
  const float qabs = (float)(q0 + l31);

  float m2 = -1e30f, lsum = 0.f;
  f32x16 acc0 = {}, acc1 = {};
  const int ktm = q0 >> 6;
  const bf8* kfb = (const bf8*)Kp + (long)bh * 16384 + lane;
  const bf8* vfb = (const bf8*)Vp + (long)bh * 16384 + lane;

  bf8 kc[8], kn[8], vc[8];
#pragma unroll
  for (int c = 0; c < 4; ++c) {
    kc[c]     = kfb[c * 64];
    kc[4 + c] = kfb[256 + c * 64];
  }

#pragma unroll 2
  for (int kt = 0; kt <= ktm; ++kt) {
    const int k0 = kt * 64;
    const long vb = (long)kt * 256;
#pragma unroll
    for (int ch = 0; ch < 4; ++ch) {
      vc[ch]     = vfb[vb + ch * 64];
      vc[4 + ch] = vfb[8192 + vb + ch * 64];
    }
    const long nb = (long)(kt < ktm ? kt + 1 : kt) * 512;
#pragma unroll
    for (int c = 0; c < 4; ++c) {
      kn[c]     = kfb[nb + c * 64];
      kn[4 + c] = kfb[nb + 256 + c * 64];
    }
    f32x16 s0 = {}, s1 = {};
#pragma unroll
    for (int c = 0; c < 4; ++c) {
      s0 = __builtin_amdgcn_mfma_f32_32x32x16_bf16(kc[c], qf[c], s0, 0, 0, 0);
      s1 = __builtin_amdgcn_mfma_f32_32x32x16_bf16(kc[4 + c], qf[c], s1, 0, 0, 0);
    }
    const float base = slope2 * ((float)k0 - qabs) + hofs;
    float s[32];
#pragma unroll
    for (int r = 0; r < 16; ++r) {
      s[r]      = fmaf(s0[r], sc2, base + arr[r]);
      s[16 + r] = fmaf(s1[r], sc2, base + arr[r] + slope2 * 32.f);
    }
    if (kt == ktm) {
      const int qi = q0 + l31;
#pragma unroll
      for (int r = 0; r < 16; ++r) {
        const int krel = (r & 3) + 8 * (r >> 2) + 4 * hi;
        if (k0 + krel > qi)      s[r]      = -1e30f;
        if (k0 + 32 + krel > qi) s[16 + r] = -1e30f;
      }
    }
    float ma = s[0], mb = s[1], mc = s[2], md = s[3];
#pragma unroll
    for (int i = 4; i < 32; i += 4) {
      ma = fmaxf(ma, s[i]); mb = fmaxf(mb, s[i + 1]);
      mc = fmaxf(mc, s[i + 2]); md = fmaxf(md, s[i + 3]);
    }
    float pm = fmaxf(fmaxf(ma, mb), fmaxf(mc, md));
    pm = fmaxf(pm, __shfl_xor(pm, 32));
    if (!__all(pm - m2 <= 11.0f)) {
      const float nm = fmaxf(m2, pm);
      const float alpha = exp2_fast(m2 - nm);
      m2 = nm;
      lsum *= alpha;
      acc0 *= alpha;
      acc1 *= alpha;
    }
    float p[32];
#pragma unroll
    for (int i = 0; i < 32; ++i) p[i] = exp2_fast(s[i] - m2);
    float sa = p[0], sb = p[1], sc = p[2], sd = p[3];
#pragma unroll
    for (int i = 4; i < 32; i += 4) {
      sa += p[i]; sb += p[i + 1]; sc += p[i + 2]; sd += p[i + 3];
    }
    float rs = (sa + sb) + (sc + sd);
    rs += __shfl_xor(rs, 32);
    lsum += rs;
    unsigned cpk[16];
#pragma unroll
    for (int g = 0; g < 8; ++g) {
      cpk[g]     = cvt_pk_bf16(p[2 * g], p[2 * g + 1]);
      cpk[8 + g] = cvt_pk_bf16(p[16 + 2 * g], p[16 + 2 * g + 1]);
    }
    bf8 pb[4];
#pragma unroll
    for (int ch = 0; ch < 4; ++ch) {
      const int cb = (ch >> 1) * 8 + (ch & 1) * 4;
      unsigned u0 = cpk[cb + 0], u2 = cpk[cb + 2];
      unsigned u1 = cpk[cb + 1], u3 = cpk[cb + 3];
      asm("v_permlane32_swap_b32 %0, %1" : "+v"(u0), "+v"(u2));
      asm("v_permlane32_swap_b32 %0, %1" : "+v"(u1), "+v"(u3));
      union { unsigned u[4]; bf8 v; } f;
      f.u[0] = u0; f.u[1] = u1; f.u[2] = u2; f.u[3] = u3;
      pb[ch] = f.v;
    }
#pragma unroll
    for (int ch = 0; ch < 4; ++ch) {
      acc0 = __builtin_amdgcn_mfma_f32_32x32x16_bf16(vc[ch], pb[ch], acc0, 0, 0, 0);
      acc1 = __builtin_amdgcn_mfma_f32_32x32x16_bf16(vc[4 + ch], pb[ch], acc1, 0, 0, 0);
    }
#pragma unroll
    for (int i = 0; i < 8; ++i) kc[i] = kn[i];
  }

  __shared__ float Os[32 * 68];
  const float rl = 1.f / lsum;
#pragma unroll
  for (int r = 0; r < 16; ++r) {
    const int d0 = (r & 3) + 8 * (r >> 2) + 4 * hi;
    Os[l31 * 68 + d0]      = acc0[r] * rl;
    Os[l31 * 68 + 32 + d0] = acc1[r] * rl;
  }
  __syncthreads();
#pragma unroll
  for (int it = 0; it < 8; ++it) {
    const int idx = it * 64 + lane;
    const int row = idx >> 4, c4 = idx & 15;
    const float4 ov = *(const float4*)&Os[row * 68 + c4 * 4];
    const long gbase = (tokbase + q0 + row) * DMODEL + h * HWID + c4 * 4;
    const short4 xv = *(const short4*)&xn[gbase];
    float4 o;
    o.x = ov.x + from_bf16(xv.x);
    o.y = ov.y + from_bf16(xv.y);
    o.z = ov.z + from_bf16(xv.z);
    o.w = ov.w + from_bf16(xv.w);
    *(float4*)&att[gbase] = o;
  }
}

// ---------------- combine: d_out += sum of 4 split-K partials ----------------
__global__ __launch_bounds__(256)
void combine_kernel(const float* __restrict__ p, float* __restrict__ dout, int n4) {
  int i = blockIdx.x * 256 + threadIdx.x;
  if (i < n4) {
    float4 a  = ((const float4*)dout)[i];
    float4 b0 = ((const float4*)(p))[i];
    float4 b1 = ((const float4*)(p + 4194304))[i];
    float4 b2 = ((const float4*)(p + 8388608))[i];
    float4 b3 = ((const float4*)(p + 12582912))[i];
    a.x += (b0.x + b1.x) + (b2.x + b3.x);
    a.y += (b0.y + b1.y) + (b2.y + b3.y);
    a.z += (b0.z + b1.z) + (b2.z + b3.z);
    a.w += (b0.w + b1.w) + (b2.w + b3.w);
    ((float4*)dout)[i] = a;
  }
}

// ---------------- launcher ----------------
extern "C" void kernel_launch(void* const* d_in, const int* in_sizes, int n_in,
                              void* d_out, int out_size, void* d_ws, size_t ws_size,
                              hipStream_t stream) {
  (void)in_sizes; (void)n_in; (void)out_size; (void)ws_size;
  const float* x  = (const float*)d_in[0];
  const float* Wq = (const float*)d_in[1];
  const float* Wk = (const float*)d_in[2];
  const float* Wv = (const float*)d_in[3];
  const float* W1 = (const float*)d_in[4];
  const float* W2 = (const float*)d_in[5];
  const float* g1 = (const float*)d_in[6];
  const float* b1 = (const float*)d_in[7];
  const float* g2 = (const float*)d_in[8];
  const float* b2 = (const float*)d_in[9];

  char* ws = (char*)d_ws;
  const size_t MB = 1024 * 1024;
  short* wqkv_b = (short*)(ws + 0);        // 6 MB [3072][1024]
  short* w1_b   = (short*)(ws + 6  * MB);  // 8 MB
  short* w2_b   = (short*)(ws + 14 * MB);  // 8 MB
  short* xn     = (short*)(ws + 22 * MB);  // 8 MB [NTOK][D]
  short* qkv    = (short*)(ws + 30 * MB);  // 24 MB [NTOK][3072]
  short* m1     = (short*)(ws + 22 * MB);  // 32 MB (aliases xn+qkv, dead after attn)
  short* Kp     = (short*)(ws + 54 * MB);  // 8 MB packed K frags (dead after attn)
  short* Vp     = (short*)(ws + 62 * MB);  // 8 MB packed V frags (dead after attn)
  short* hb     = (short*)(ws + 70 * MB);  // 8 MB (dead after mlp1)
  float* parts  = (float*)(ws + 54 * MB);  // 64 MB (aliases Kp/Vp/hb)
  float* att    = (float*)d_out;           // att lives in d_out (combine residual)

  cvt_all<<<11264, 256, 0, stream>>>(Wq, Wk, Wv, W1, W2, wqkv_b, w1_b, w2_b);

  ln_kernel<<<NTOK, 256, 0, stream>>>(x, g1, b1, xn);

  // fused QKV: [NTOK][3072]
  gemm4<0><<<dim3(24, 16), 256, 0, stream>>>(xn, wqkv_b, qkv, QKLD, DMODEL, DMODEL,
                                             DMODEL, 0);
  pack_kv<<<dim3(96, 32), 256, 0, stream>>>(qkv, Kp, Vp);

  attn_kernel<<<2048, 64, 0, stream>>>(qkv, Kp, Vp, xn, att);

  ln_kernel<<<NTOK, 256, 0, stream>>>(att, g2, b2, hb);

  // MLP1: m1 = silu(hb * w1^T)
  gemm4<1><<<dim3(32, 16), 256, 0, stream>>>(hb, w1_b, m1, FFDIM, DMODEL, DMODEL,
                                             DMODEL, 0);
  // MLP2 split-K=4 into parts, then combine with att residual (in d_out)
  gemm4<2><<<dim3(8, 16, 4), 256, 0, stream>>>(m1, w2_b, parts, DMODEL, FFDIM, FFDIM,
                                               1024, (long)NTOK * DMODEL);
  combine_kernel<<<4096, 256, 0, stream>>>(parts, (float*)d_out, 1048576);
}

// Round 8
// 204.843 us; speedup vs baseline: 1.1338x; 1.0009x over previous
//
#include <hip/hip_runtime.h>

#define DMODEL 1024
#define NHEAD  16
#define HWID   64
#define FFDIM  4096
#define NBATCH 2
#define SEQT   2048
#define NTOK   4096   // NBATCH*SEQT
#define QKLD   3072   // qkv row stride

using bf8    = __attribute__((ext_vector_type(8))) short;
using f32x4  = __attribute__((ext_vector_type(4))) float;
using f32x16 = __attribute__((ext_vector_type(16))) float;

__device__ inline short to_bf16(float f) {
  unsigned u = __float_as_uint(f);
  return (short)((u + 0x7fffu + ((u >> 16) & 1u)) >> 16);
}
__device__ inline float from_bf16(short s) {
  return __uint_as_float(((unsigned)(unsigned short)s) << 16);
}
__device__ inline float exp2_fast(float x) {
  float r;
  asm("v_exp_f32 %0, %1" : "=v"(r) : "v"(x));
  return r;
}
__device__ inline unsigned cvt_pk_bf16(float lo, float hi) {
  unsigned r;
  asm("v_cvt_pk_bf16_f32 %0, %1, %2" : "=v"(r) : "v"(lo), "v"(hi));
  return r;
}
__device__ inline void lds_load16(const void* g, void* l) {
  __builtin_amdgcn_global_load_lds(
      (const __attribute__((address_space(1))) void*)g,
      (__attribute__((address_space(3))) void*)l, 16, 0, 0);
}

// ---------------- all weights f32 -> bf16 in one launch ----------------
__global__ __launch_bounds__(256)
void cvt_all(const float* __restrict__ Wq, const float* __restrict__ Wk,
             const float* __restrict__ Wv, const float* __restrict__ W1,
             const float* __restrict__ W2, short* __restrict__ wqkv,
             short* __restrict__ w1b, short* __restrict__ w2b) {
  int i = blockIdx.x * 256 + threadIdx.x;   // float4 index, total 2883584
  const float* src;
  short* dst;
  if (i < 1048576)      { src = W1; dst = w1b; }
  else if (i < 2097152) { src = W2; dst = w2b;            i -= 1048576; }
  else if (i < 2359296) { src = Wq; dst = wqkv;           i -= 2097152; }
  else if (i < 2621440) { src = Wk; dst = wqkv + 1048576; i -= 2359296; }
  else                  { src = Wv; dst = wqkv + 2097152; i -= 2621440; }
  float4 v = ((const float4*)src)[i];
  short4 o;
  o.x = to_bf16(v.x); o.y = to_bf16(v.y);
  o.z = to_bf16(v.z); o.w = to_bf16(v.w);
  ((short4*)dst)[i] = o;
}

// ---------------- LayerNorm (f32 in -> bf16 out) ----------------
__global__ __launch_bounds__(256)
void ln_kernel(const float* __restrict__ x, const float* __restrict__ g,
               const float* __restrict__ b, short* __restrict__ out) {
  const int row = blockIdx.x;
  const int t = threadIdx.x;
  const float4 v = ((const float4*)(x + (long)row * DMODEL))[t];
  float s  = v.x + v.y + v.z + v.w;
  float s2 = v.x * v.x + v.y * v.y + v.z * v.z + v.w * v.w;
#pragma unroll
  for (int m = 1; m < 64; m <<= 1) {
    s  += __shfl_xor(s, m);
    s2 += __shfl_xor(s2, m);
  }
  __shared__ float red[8];
  if ((t & 63) == 0) { red[t >> 6] = s; red[4 + (t >> 6)] = s2; }
  __syncthreads();
  s  = red[0] + red[1] + red[2] + red[3];
  s2 = red[4] + red[5] + red[6] + red[7];
  const float mu = s * (1.f / DMODEL);
  const float rs = rsqrtf(s2 * (1.f / DMODEL) - mu * mu + 1e-5f);
  const float4 gv = ((const float4*)g)[t];
  const float4 bv = ((const float4*)b)[t];
  short4 o;
  o.x = to_bf16((v.x - mu) * rs * gv.x + bv.x);
  o.y = to_bf16((v.y - mu) * rs * gv.y + bv.y);
  o.z = to_bf16((v.z - mu) * rs * gv.z + bv.z);
  o.w = to_bf16((v.w - mu) * rs * gv.w + bv.w);
  ((short4*)(out + (long)row * DMODEL))[t] = o;
}

// ---- 8-wave 256x256 NT GEMM, BK=32, ring-4 LDS, register frag read-ahead.
// Wave tile 128x64. One vmcnt+barrier per K-tile; MFMAs run on frags read the
// previous iteration while this iteration's ds_reads + gloads fill the pipes.
// EPI 0: bf16 store; 1: SiLU bf16; 2: f32 store into parts + z*zstride.
template <int EPI>
__global__ __launch_bounds__(512, 2)
void gemm8r(const short* __restrict__ A, const short* __restrict__ Bw,
            void* __restrict__ Cout, int N, int lda, int ldb, int Kslice,
            long zstride) {
  __shared__ short lds[4][16384];   // slot: A[256][32] @0 | B[256][32] @16384B
  const int tid = threadIdx.x;
  const int wid = tid >> 6, lane = tid & 63;
  const int l15 = lane & 15, l4 = lane >> 4;
  const int wm = wid >> 2, wn = wid & 3;   // wave tile rows wm*128, cols wn*64

  // XCD chunk + 4x4 supertile (gx%4==0, nwg%8==0)
  const int gx = gridDim.x, nwg = gx * gridDim.y;
  const int wg = blockIdx.y * gx + blockIdx.x;
  const int sw = (wg & 7) * (nwg >> 3) + (wg >> 3);
  const int sx = gx >> 2;
  const int st = sw >> 4, w16 = sw & 15;
  const long bm = (long)((st / sx) * 4 + (w16 >> 2)) * 256;
  const long bn = (long)((st % sx) * 4 + (w16 & 3)) * 256;
  const long kofs = (long)blockIdx.z * Kslice;

  // staging: 2 granule-passes per operand, source pre-swizzled, LDS dest linear
  long aoff[2], boff[2];
  int  doff[2];
#pragma unroll
  for (int l = 0; l < 2; ++l) {
    const int gid = l * 512 + tid;           // 0..1023 granules of 16B
    const int row = gid >> 2;
    const int sg = (gid & 3) ^ ((row >> 1) & 3);
    aoff[l] = (bm + row) * (long)lda + kofs + sg * 8;
    boff[l] = (bn + row) * (long)ldb + kofs + sg * 8;
    doff[l] = gid * 16;
  }
  // swizzled LDS read byte-offsets
  int offA[8], offB[4];
#pragma unroll
  for (int m = 0; m < 8; ++m) {
    const int row = wm * 128 + m * 16 + l15;
    offA[m] = row * 64 + ((l4 ^ ((row >> 1) & 3)) << 4);
  }
#pragma unroll
  for (int n = 0; n < 4; ++n) {
    const int row = wn * 64 + n * 16 + l15;
    offB[n] = row * 64 + ((l4 ^ ((row >> 1) & 3)) << 4);
  }

  const int NT = Kslice >> 5;   // even, >= 4
  f32x4 acc[8][4] = {};
  bf8 fa0[8], fb0[4], fa1[8], fb1[4];

  // prologue: stage tiles 0,1,2 ; wait tile0 ; read frags(0)
#pragma unroll
  for (int tt = 0; tt < 3; ++tt) {
    char* db = (char*)&lds[tt][0];
#pragma unroll
    for (int l = 0; l < 2; ++l) {
      lds_load16(A  + aoff[l] + tt * 32, db + doff[l]);
      lds_load16(Bw + boff[l] + tt * 32, db + 16384 + doff[l]);
    }
  }
  asm volatile("s_waitcnt vmcnt(8)" ::: "memory");
  __builtin_amdgcn_s_barrier();
  asm volatile("" ::: "memory");
  {
    const char* sb = (const char*)&lds[0][0];
#pragma unroll
    for (int m = 0; m < 8; ++m) fa0[m] = *(const bf8*)(sb + offA[m]);
#pragma unroll
    for (int n = 0; n < 4; ++n) fb0[n] = *(const bf8*)(sb + 16384 + offB[n]);
  }

  auto step = [&](int t, bf8 (&ca)[8], bf8 (&cb)[4],
                  bf8 (&na)[8], bf8 (&nb)[4]) {
    // tile t+1's staging (issued at t-2) must be drained; t+2's may remain
    if (t + 3 < NT) asm volatile("s_waitcnt vmcnt(4)" ::: "memory");
    else            asm volatile("s_waitcnt vmcnt(0)" ::: "memory");
    __builtin_amdgcn_s_barrier();
    asm volatile("" ::: "memory");
    if (t + 3 < NT) {                        // stage tile t+3 into its slot
      char* db = (char*)&lds[(t + 3) & 3][0];
      const long ks = (long)(t + 3) * 32;
#pragma unroll
      for (int l = 0; l < 2; ++l) {
        lds_load16(A  + aoff[l] + ks, db + doff[l]);
        lds_load16(Bw + boff[l] + ks, db + 16384 + doff[l]);
      }
    }
    if (t + 1 < NT) {                        // read next tile's frags
      const char* sb = (const char*)&lds[(t + 1) & 3][0];
#pragma unroll
      for (int m = 0; m < 8; ++m) na[m] = *(const bf8*)(sb + offA[m]);
#pragma unroll
      for (int n = 0; n < 4; ++n) nb[n] = *(const bf8*)(sb + 16384 + offB[n]);
    }
    __builtin_amdgcn_sched_barrier(0);       // pin reads+stages above MFMAs
    __builtin_amdgcn_s_setprio(1);
#pragma unroll
    for (int m = 0; m < 8; ++m)
#pragma unroll
      for (int n = 0; n < 4; ++n)
        acc[m][n] = __builtin_amdgcn_mfma_f32_16x16x32_bf16(ca[m], cb[n], acc[m][n], 0, 0, 0);
    __builtin_amdgcn_s_setprio(0);
  };

  for (int t = 0; t < NT; t += 2) {          // named frag sets: static indexing
    step(t,     fa0, fb0, fa1, fb1);
    step(t + 1, fa1, fb1, fa0, fb0);
  }

  // ---------- epilogue ----------
  float* Cp = (float*)Cout + (EPI == 2 ? (long)blockIdx.z * zstride : 0);
#pragma unroll
  for (int m = 0; m < 8; ++m)
#pragma unroll
    for (int n = 0; n < 4; ++n) {
      const long col = bn + wn * 64 + n * 16 + l15;
#pragma unroll
      for (int r = 0; r < 4; ++r) {
        const long row = bm + wm * 128 + m * 16 + l4 * 4 + r;
        float v = acc[m][n][r];
        if (EPI == 0) {
          ((short*)Cout)[row * N + col] = to_bf16(v);
        } else if (EPI == 1) {
          ((short*)Cout)[row * N + col] = to_bf16(v / (1.f + __expf(-v)));
        } else {
          Cp[row * N + col] = v;
        }
      }
    }
}

// ---------------- K pack + V pack, one launch ----------------
__global__ __launch_bounds__(256)
void pack_kv(const short* __restrict__ qkv, short* __restrict__ Kp,
             short* __restrict__ Vp) {
  __shared__ short tile[64][72];
  const int bx = blockIdx.x, bh = blockIdx.y;
  const int b = bh >> 4, h = bh & 15;
  const int t = threadIdx.x;
  if (bx < 64) {
    const int g = bx;
    const int row = t >> 3, cc = t & 7, c = cc >> 1, hi = cc & 1;
    const bf8 v = *(const bf8*)&qkv[(long)(b * SEQT + g * 32 + row) * QKLD +
                                    1024 + h * HWID + c * 16 + hi * 8];
    *(bf8*)&Kp[(((long)bh * 256 + g * 4 + c) * 64 + hi * 32 + row) * 8] = v;
  } else {
    const int tc = bx - 64;
    {
      const int r = t >> 2, c = (t & 3) * 16;
      const long src = (long)(b * SEQT + tc * 64 + r) * QKLD + 2048 + h * HWID + c;
      *(bf8*)&tile[r][c]     = *(const bf8*)&qkv[src];
      *(bf8*)&tile[r][c + 8] = *(const bf8*)&qkv[src + 8];
    }
    __syncthreads();
    const int dg = t >> 7, ch = (t >> 5) & 3, row = t & 31;
#pragma unroll
    for (int hi = 0; hi < 2; ++hi) {
      short o[8];
#pragma unroll
      for (int j = 0; j < 8; ++j) o[j] = tile[ch * 16 + hi * 8 + j][dg * 32 + row];
      *(bf8*)&Vp[(((long)bh * 256 + dg * 128 + tc * 4 + ch) * 64 + hi * 32 + row) * 8] =
          *(bf8*)o;
    }
  }
}

// ---------------- Flash attention: 1 warp = 32 q rows, packed K/V frags ----
__global__ __launch_bounds__(64, 2)
void attn_kernel(const short* __restrict__ qkv, const short* __restrict__ Kp,
                 const short* __restrict__ Vp, const short* __restrict__ xn,
                 float* __restrict__ att) {
  const int L = blockIdx.x;
  const int bh = (L & 7) * 4 + ((L >> 3) & 3);
  const int qtile = 63 - (L >> 5);
  const int b = bh >> 4, h = bh & 15;
  const int q0 = qtile * 32;
  const int lane = threadIdx.x;
  const int l31 = lane & 31, hi = lane >> 5;
  const long tokbase = (long)b * SEQT;

  bf8 qf[4];
  {
    const short* qrow = qkv + (tokbase + q0 + l31) * QKLD + h * HWID + hi * 8;
#pragma unroll
    for (int c = 0; c < 4; ++c) qf[c] = *(const bf8*)(qrow + c * 16);
  }

  const float slope2 = exp2f(-0.5f * (float)(h + 1)) * 1.44269504f;
  const float sc2 = 0.125f * 1.44269504f;
  float arr[16];
#pragma unroll
  for (int r = 0; r < 16; ++r) arr[r] = slope2 * (float)((r & 3) + 8 * (r >> 2));
  const float hofs = slope2 * 4.f * (float)hi;
  const float qabs = (float)(q0 + l31);

  float m2 = -1e30f, lsum = 0.f;
  f32x16 acc0 = {}, acc1 = {};
  const int ktm = q0 >> 6;
  const bf8* kfb = (const bf8*)Kp + (long)bh * 16384 + lane;
  const bf8* vfb = (const bf8*)Vp + (long)bh * 16384 + lane;

  bf8 kc[8], kn[8], vc[8];
#pragma unroll
  for (int c = 0; c < 4; ++c) {
    kc[c]     = kfb[c * 64];
    kc[4 + c] = kfb[256 + c * 64];
  }

#pragma unroll 2
  for (int kt = 0; kt <= ktm; ++kt) {
    const int k0 = kt * 64;
    const long vb = (long)kt * 256;
#pragma unroll
    for (int ch = 0; ch < 4; ++ch) {
      vc[ch]     = vfb[vb + ch * 64];
      vc[4 + ch] = vfb[8192 + vb + ch * 64];
    }
    const long nb = (long)(kt < ktm ? kt + 1 : kt) * 512;
#pragma unroll
    for (int c = 0; c < 4; ++c) {
      kn[c]     = kfb[nb + c * 64];
      kn[4 + c] = kfb[nb + 256 + c * 64];
    }
    f32x16 s0 = {}, s1 = {};
#pragma unroll
    for (int c = 0; c < 4; ++c) {
      s0 = __builtin_amdgcn_mfma_f32_32x32x16_bf16(kc[c], qf[c], s0, 0, 0, 0);
      s1 = __builtin_amdgcn_mfma_f32_32x32x16_bf16(kc[4 + c], qf[c], s1, 0, 0, 0);
    }
    const float base = slope2 * ((float)k0 - qabs) + hofs;
    float s[32];
#pragma unroll
    for (int r = 0; r < 16; ++r) {
      s[r]      = fmaf(s0[r], sc2, base + arr[r]);
      s[16 + r] = fmaf(s1[r], sc2, base + arr[r] + slope2 * 32.f);
    }
    if (kt == ktm) {
      const int qi = q0 + l31;
#pragma unroll
      for (int r = 0; r < 16; ++r) {
        const int krel = (r & 3) + 8 * (r >> 2) + 4 * hi;
        if (k0 + krel > qi)      s[r]      = -1e30f;
        if (k0 + 32 + krel > qi) s[16 + r] = -1e30f;
      }
    }
    float ma = s[0], mb = s[1], mc = s[2], md = s[3];
#pragma unroll
    for (int i = 4; i < 32; i += 4) {
      ma = fmaxf(ma, s[i]); mb = fmaxf(mb, s[i + 1]);
      mc = fmaxf(mc, s[i + 2]); md = fmaxf(md, s[i + 3]);
    }
    float pm = fmaxf(fmaxf(ma, mb), fmaxf(mc, md));
    pm = fmaxf(pm, __shfl_xor(pm, 32));
    if (!__all(pm - m2 <= 11.0f)) {
      const float nm = fmaxf(m2, pm);
      const float alpha = exp2_fast(m2 - nm);
      m2 = nm;
      lsum *= alpha;
      acc0 *= alpha;
      acc1 *= alpha;
    }
    float p[32];
#pragma unroll
    for (int i = 0; i < 32; ++i) p[i] = exp2_fast(s[i] - m2);
    float sa = p[0], sb = p[1], sc = p[2], sd = p[3];
#pragma unroll
    for (int i = 4; i < 32; i += 4) {
      sa += p[i]; sb += p[i + 1]; sc += p[i + 2]; sd += p[i + 3];
    }
    float rs = (sa + sb) + (sc + sd);
    rs += __shfl_xor(rs, 32);
    lsum += rs;
    unsigned cpk[16];
#pragma unroll
    for (int g = 0; g < 8; ++g) {
      cpk[g]     = cvt_pk_bf16(p[2 * g], p[2 * g + 1]);
      cpk[8 + g] = cvt_pk_bf16(p[16 + 2 * g], p[16 + 2 * g + 1]);
    }
    bf8 pb[4];
#pragma unroll
    for (int ch = 0; ch < 4; ++ch) {
      const int cb = (ch >> 1) * 8 + (ch & 1) * 4;
      unsigned u0 = cpk[cb + 0], u2 = cpk[cb + 2];
      unsigned u1 = cpk[cb + 1], u3 = cpk[cb + 3];
      asm("v_permlane32_swap_b32 %0, %1" : "+v"(u0), "+v"(u2));
      asm("v_permlane32_swap_b32 %0, %1" : "+v"(u1), "+v"(u3));
      union { unsigned u[4]; bf8 v; } f;
      f.u[0] = u0; f.u[1] = u1; f.u[2] = u2; f.u[3] = u3;
      pb[ch] = f.v;
    }
#pragma unroll
    for (int ch = 0; ch < 4; ++ch) {
      acc0 = __builtin_amdgcn_mfma_f32_32x32x16_bf16(vc[ch], pb[ch], acc0, 0, 0, 0);
      acc1 = __builtin_amdgcn_mfma_f32_32x32x16_bf16(vc[4 + ch], pb[ch], acc1, 0, 0, 0);
    }
#pragma unroll
    for (int i = 0; i < 8; ++i) kc[i] = kn[i];
  }

  __shared__ float Os[32 * 68];
  const float rl = 1.f / lsum;
#pragma unroll
  for (int r = 0; r < 16; ++r) {
    const int d0 = (r & 3) + 8 * (r >> 2) + 4 * hi;
    Os[l31 * 68 + d0]      = acc0[r] * rl;
    Os[l31 * 68 + 32 + d0] = acc1[r] * rl;
  }
  __syncthreads();
#pragma unroll
  for (int it = 0; it < 8; ++it) {
    const int idx = it * 64 + lane;
    const int row = idx >> 4, c4 = idx & 15;
    const float4 ov = *(const float4*)&Os[row * 68 + c4 * 4];
    const long gbase = (tokbase + q0 + row) * DMODEL + h * HWID + c4 * 4;
    const short4 xv = *(const short4*)&xn[gbase];
    float4 o;
    o.x = ov.x + from_bf16(xv.x);
    o.y = ov.y + from_bf16(xv.y);
    o.z = ov.z + from_bf16(xv.z);
    o.w = ov.w + from_bf16(xv.w);
    *(float4*)&att[gbase] = o;
  }
}

// ---------------- combine: d_out += sum of 4 split-K partials ----------------
__global__ __launch_bounds__(256)
void combine_kernel(const float* __restrict__ p, float* __restrict__ dout, int n4) {
  int i = blockIdx.x * 256 + threadIdx.x;
  if (i < n4) {
    float4 a  = ((const float4*)dout)[i];
    float4 b0 = ((const float4*)(p))[i];
    float4 b1 = ((const float4*)(p + 4194304))[i];
    float4 b2 = ((const float4*)(p + 8388608))[i];
    float4 b3 = ((const float4*)(p + 12582912))[i];
    a.x += (b0.x + b1.x) + (b2.x + b3.x);
    a.y += (b0.y + b1.y) + (b2.y + b3.y);
    a.z += (b0.z + b1.z) + (b2.z + b3.z);
    a.w += (b0.w + b1.w) + (b2.w + b3.w);
    ((float4*)dout)[i] = a;
  }
}

// ---------------- launcher ----------------
extern "C" void kernel_launch(void* const* d_in, const int* in_sizes, int n_in,
                              void* d_out, int out_size, void* d_ws, size_t ws_size,
                              hipStream_t stream) {
  (void)in_sizes; (void)n_in; (void)out_size; (void)ws_size;
  const float* x  = (const float*)d_in[0];
  const float* Wq = (const float*)d_in[1];
  const float* Wk = (const float*)d_in[2];
  const float* Wv = (const float*)d_in[3];
  const float* W1 = (const float*)d_in[4];
  const float* W2 = (const float*)d_in[5];
  const float* g1 = (const float*)d_in[6];
  const float* b1 = (const float*)d_in[7];
  const float* g2 = (const float*)d_in[8];
  const float* b2 = (const float*)d_in[9];

  char* ws = (char*)d_ws;
  const size_t MB = 1024 * 1024;
  short* wqkv_b = (short*)(ws + 0);        // 6 MB [3072][1024]
  short* w1_b   = (short*)(ws + 6  * MB);  // 8 MB
  short* w2_b   = (short*)(ws + 14 * MB);  // 8 MB
  short* xn     = (short*)(ws + 22 * MB);  // 8 MB [NTOK][D]
  short* qkv    = (short*)(ws + 30 * MB);  // 24 MB [NTOK][3072]
  short* m1     = (short*)(ws + 22 * MB);  // 32 MB (aliases xn+qkv, dead after attn)
  short* Kp     = (short*)(ws + 54 * MB);  // 8 MB packed K frags (dead after attn)
  short* Vp     = (short*)(ws + 62 * MB);  // 8 MB packed V frags (dead after attn)
  short* hb     = (short*)(ws + 70 * MB);  // 8 MB (dead after mlp1)
  float* parts  = (float*)(ws + 54 * MB);  // 64 MB (aliases Kp/Vp/hb)
  float* att    = (float*)d_out;           // att lives in d_out (combine residual)

  cvt_all<<<11264, 256, 0, stream>>>(Wq, Wk, Wv, W1, W2, wqkv_b, w1_b, w2_b);

  ln_kernel<<<NTOK, 256, 0, stream>>>(x, g1, b1, xn);

  // fused QKV: [NTOK][3072]
  gemm8r<0><<<dim3(12, 16), 512, 0, stream>>>(xn, wqkv_b, qkv, QKLD, DMODEL, DMODEL,
                                              DMODEL, 0);
  pack_kv<<<dim3(96, 32), 256, 0, stream>>>(qkv, Kp, Vp);

  attn_kernel<<<2048, 64, 0, stream>>>(qkv, Kp, Vp, xn, att);

  ln_kernel<<<NTOK, 256, 0, stream>>>(att, g2, b2, hb);

  // MLP1: m1 = silu(hb * w1^T)
  gemm8r<1><<<dim3(16, 16), 512, 0, stream>>>(hb, w1_b, m1, FFDIM, DMODEL, DMODEL,
                                              DMODEL, 0);
  // MLP2 split-K=4 into parts, then combine with att residual (in d_out)
  gemm8r<2><<<dim3(4, 16, 4), 512, 0, stream>>>(m1, w2_b, parts, DMODEL, FFDIM, FFDIM,
                                                1024, (long)NTOK * DMODEL);
  combine_kernel<<<4096, 256, 0, stream>>>(parts, (float*)d_out, 1048576);
}